// Round 1
// baseline (981.442 us; speedup 1.0000x reference)
//
#include <hip/hip_runtime.h>

#define S_LEN 1024
#define HIDN  4096
#define NH    64
#define HD    64
#define NCH   16     // chunks
#define CLEN  64     // steps per chunk

typedef short bf16x8 __attribute__((ext_vector_type(8)));
typedef float f32x4  __attribute__((ext_vector_type(4)));

__device__ __forceinline__ unsigned short f2bf(float x){
  unsigned u = __float_as_uint(x);
  u += 0x7fffu + ((u >> 16) & 1u);   // round-to-nearest-even
  return (unsigned short)(u >> 16);
}

// ---------------- token-mix prepass: mixed[z][s][i] (bf16) -------------------
__global__ __launch_bounds__(256)
void mix_kernel(const float* __restrict__ hidden,
                const float* __restrict__ tmk, const float* __restrict__ tmv,
                const float* __restrict__ tmr, const float* __restrict__ tmg,
                unsigned short* __restrict__ mixed)
{
  int idx = blockIdx.x * 256 + threadIdx.x;      // 0 .. S*HID-1
  int i = idx & (HIDN - 1);
  float h  = hidden[idx];
  float sh = (idx >= HIDN) ? hidden[idx - HIDN] : 0.f;
  float mk = tmk[i], mv = tmv[i], mr = tmr[i], mg = tmg[i];
  mixed[idx + 0 * S_LEN * HIDN] = f2bf(h * mk + sh * (1.f - mk));
  mixed[idx + 1 * S_LEN * HIDN] = f2bf(h * mv + sh * (1.f - mv));
  mixed[idx + 2 * S_LEN * HIDN] = f2bf(h * mr + sh * (1.f - mr));
  mixed[idx + 3 * S_LEN * HIDN] = f2bf(h * mg + sh * (1.f - mg));
}

// ------------- GEMM: C[z] = A[z](MxK bf16) @ W[z](NxK fp32)^T ----------------
// 128x128 tile, BK=32, 4 waves (2x2 of 64x64), 4x4 16x16x32 mfma frags/wave.
// W is converted fp32->bf16 during LDS staging.
__global__ __launch_bounds__(256)
void gemm_bt(const unsigned short* __restrict__ Aall,
             const float* __restrict__ W0, const float* __restrict__ W1,
             const float* __restrict__ W2, const float* __restrict__ W3,
             float* __restrict__ Call, int M, int K, int N, int silu_mask)
{
  const int z = blockIdx.z;
  const float* __restrict__ W = (z == 0) ? W0 : (z == 1) ? W1 : (z == 2) ? W2 : W3;
  const unsigned short* __restrict__ A = Aall + (size_t)z * M * K;
  float* __restrict__ C = Call + (size_t)z * M * N;
  const int m0 = blockIdx.x * 128;
  const int n0 = blockIdx.y * 128;

  __shared__ unsigned short As[128 * 32];   // 8 KB
  __shared__ unsigned short Bs[128 * 32];   // 8 KB

  const int tid  = threadIdx.x;
  const int lane = tid & 63;
  const int wave = tid >> 6;
  const int wr = (wave >> 1) * 64;   // wave row offset in tile
  const int wc = (wave & 1) * 64;    // wave col offset in tile
  const int fr = lane & 15;          // fragment row (m) / col (n)
  const int fk = (lane >> 4) * 8;    // fragment k offset

  f32x4 acc[4][4];
#pragma unroll
  for (int mi = 0; mi < 4; ++mi)
#pragma unroll
    for (int ni = 0; ni < 4; ++ni) acc[mi][ni] = (f32x4){0.f, 0.f, 0.f, 0.f};

  for (int k0 = 0; k0 < K; k0 += 32) {
    // stage A tile: 128x32 bf16 = 512 x 16B units, 2 per thread
#pragma unroll
    for (int u = 0; u < 2; ++u) {
      int q = u * 256 + tid;
      int row = q >> 2, c8 = (q & 3) * 8;
      *(int4*)(&As[q * 8]) = *(const int4*)(&A[(size_t)(m0 + row) * K + k0 + c8]);
    }
    // stage B tile: 128x32 fp32 -> bf16, 1024 float4 units, 4 per thread
#pragma unroll
    for (int u = 0; u < 4; ++u) {
      int q = u * 256 + tid;
      int row = q >> 3, c4 = (q & 7) * 4;
      float4 f = *(const float4*)(&W[(size_t)(n0 + row) * K + k0 + c4]);
      uint2 p;
      p.x = (unsigned)f2bf(f.x) | ((unsigned)f2bf(f.y) << 16);
      p.y = (unsigned)f2bf(f.z) | ((unsigned)f2bf(f.w) << 16);
      *(uint2*)(&Bs[q * 4]) = p;
    }
    __syncthreads();

    bf16x8 af[4], bq[4];
#pragma unroll
    for (int mi = 0; mi < 4; ++mi)
      af[mi] = *(const bf16x8*)(&As[(wr + mi * 16 + fr) * 32 + fk]);
#pragma unroll
    for (int ni = 0; ni < 4; ++ni)
      bq[ni] = *(const bf16x8*)(&Bs[(wc + ni * 16 + fr) * 32 + fk]);
#pragma unroll
    for (int mi = 0; mi < 4; ++mi)
#pragma unroll
      for (int ni = 0; ni < 4; ++ni)
        acc[mi][ni] = __builtin_amdgcn_mfma_f32_16x16x32_bf16(af[mi], bq[ni], acc[mi][ni], 0, 0, 0);
    __syncthreads();
  }

  const bool do_silu = (silu_mask >> z) & 1;
  const int orow = (lane >> 4) * 4;
#pragma unroll
  for (int mi = 0; mi < 4; ++mi)
#pragma unroll
    for (int ni = 0; ni < 4; ++ni)
#pragma unroll
      for (int r = 0; r < 4; ++r) {
        int row = m0 + wr + mi * 16 + orow + r;
        int col = n0 + wc + ni * 16 + fr;
        float v = acc[mi][ni][r];
        if (do_silu) v = v / (1.f + __expf(-v));
        C[(size_t)row * N + col] = v;
      }
}

// -------------------- recurrence pass 1: local chunk states ------------------
// block (c,h), 64 lanes = e. st[d] in regs. X[c][h][d][e] = chunk-local final state.
__global__ __launch_bounds__(64)
void rec_pass1(const float* __restrict__ kb, const float* __restrict__ vb,
               const float* __restrict__ time_decay, float* __restrict__ X)
{
  const int c = blockIdx.x, h = blockIdx.y, e = threadIdx.x;
  float td[64];
#pragma unroll
  for (int d = 0; d < 64; ++d) td[d] = __expf(-__expf(time_decay[h * 64 + d]));
  float st[64];
#pragma unroll
  for (int d = 0; d < 64; ++d) st[d] = 0.f;

  for (int t = c * CLEN; t < c * CLEN + CLEN; ++t) {
    const size_t off = (size_t)t * HIDN + h * 64;
    const float vl = vb[off + e];
    const float* __restrict__ krow = kb + off;   // uniform loads over d
#pragma unroll
    for (int d = 0; d < 64; ++d)
      st[d] = fmaf(td[d], st[d], krow[d] * vl);
  }
#pragma unroll
  for (int d = 0; d < 64; ++d)
    X[(((size_t)c * NH + h) * 64 + d) * 64 + e] = st[d];
}

// ------------- recurrence pass 2: scan boundary states across chunks ---------
// Y[c] = state entering chunk c. td^64 = exp(-64*exp(decay)).
__global__ __launch_bounds__(64)
void rec_pass2(const float* __restrict__ time_decay,
               const float* __restrict__ X, float* __restrict__ Y)
{
  const int h = blockIdx.x, e = threadIdx.x;
  float td64[64];
#pragma unroll
  for (int d = 0; d < 64; ++d) td64[d] = __expf(-64.f * __expf(time_decay[h * 64 + d]));
  float acc[64];
#pragma unroll
  for (int d = 0; d < 64; ++d) acc[d] = 0.f;
  for (int c = 0; c < NCH; ++c) {
#pragma unroll
    for (int d = 0; d < 64; ++d) {
      size_t idx = (((size_t)c * NH + h) * 64 + d) * 64 + e;
      Y[idx] = acc[d];
      acc[d] = fmaf(td64[d], acc[d], X[idx]);
    }
  }
}

// ------- recurrence pass 3: outputs + fused GroupNorm + gate -> A2 (bf16) ----
__global__ __launch_bounds__(64)
void rec_pass3(const float* __restrict__ kb, const float* __restrict__ vb,
               const float* __restrict__ rb, const float* __restrict__ gb,
               const float* __restrict__ time_decay, const float* __restrict__ time_faaaa,
               const float* __restrict__ gnw, const float* __restrict__ gnb,
               const float* __restrict__ Y, unsigned short* __restrict__ A2)
{
  const int c = blockIdx.x, h = blockIdx.y, e = threadIdx.x;
  float td[64];
#pragma unroll
  for (int d = 0; d < 64; ++d) td[d] = __expf(-__expf(time_decay[h * 64 + d]));
  float st[64];
#pragma unroll
  for (int d = 0; d < 64; ++d)
    st[d] = Y[(((size_t)c * NH + h) * 64 + d) * 64 + e];

  const float tf_l  = time_faaaa[h * 64 + e];
  const float gnw_l = gnw[h * 64 + e];
  const float gnb_l = gnb[h * 64 + e];

  for (int t = c * CLEN; t < c * CLEN + CLEN; ++t) {
    const size_t off = (size_t)t * HIDN + h * 64;
    const float kl = kb[off + e], rl = rb[off + e];
    const float vl = vb[off + e], gl = gb[off + e];

    // A = sum_d r[d]*tf[d]*k[d]  (handles the tf .* (k v^T) term: o += A*v[e])
    float Asum = rl * tf_l * kl;
#pragma unroll
    for (int i = 1; i < 64; i <<= 1) Asum += __shfl_xor(Asum, i, 64);

    const float* __restrict__ krow = kb + off;   // uniform over d -> s_load
    const float* __restrict__ rrow = rb + off;
    float dot = 0.f;
#pragma unroll
    for (int d = 0; d < 64; ++d) {
      dot   = fmaf(rrow[d], st[d], dot);                 // uses state_{t-1}
      st[d] = fmaf(td[d], st[d], krow[d] * vl);          // state_t
    }
    float o = fmaf(Asum, vl, dot);

    // GroupNorm over the head (the 64 lanes of this wave)
    float s1 = o, s2 = o * o;
#pragma unroll
    for (int i = 1; i < 64; i <<= 1) {
      s1 += __shfl_xor(s1, i, 64);
      s2 += __shfl_xor(s2, i, 64);
    }
    float mean = s1 * (1.f / 64.f);
    float var  = s2 * (1.f / 64.f) - mean * mean;
    float xn   = (o - mean) * rsqrtf(var + 1e-5f);
    float yv   = xn * gnw_l + gnb_l;
    A2[off + e] = f2bf(gl * yv);
  }
}

// -----------------------------------------------------------------------------
extern "C" void kernel_launch(void* const* d_in, const int* in_sizes, int n_in,
                              void* d_out, int out_size, void* d_ws, size_t ws_size,
                              hipStream_t stream)
{
  const float* hidden     = (const float*)d_in[0];
  const float* w_key      = (const float*)d_in[1];
  const float* w_value    = (const float*)d_in[2];
  const float* w_recep    = (const float*)d_in[3];
  const float* w_gate     = (const float*)d_in[4];
  const float* w_output   = (const float*)d_in[5];
  const float* tmk        = (const float*)d_in[6];
  const float* tmv        = (const float*)d_in[7];
  const float* tmr        = (const float*)d_in[8];
  const float* tmg        = (const float*)d_in[9];
  const float* time_decay = (const float*)d_in[10];
  const float* time_faaaa = (const float*)d_in[11];
  const float* gnw        = (const float*)d_in[12];
  const float* gnb        = (const float*)d_in[13];
  float* out = (float*)d_out;

  char* ws = (char*)d_ws;
  // layout (bytes):
  //   mixed bf16 [4][S][HID]          @ 0         (33,554,432)
  //   kvrg  f32  [4][S][HID]          @ 33554432  (67,108,864)
  //   X     f32  [16][64][64][64]     @ 100663296 (16,777,216)
  //   Y     f32  [16][64][64][64]     @ 117440512 (16,777,216)
  //   A2    bf16 [S][HID]             @ 134217728 (8,388,608)  -> total 142.6 MB
  unsigned short* mixed = (unsigned short*)(ws);
  float*          kvrg  = (float*)(ws + 33554432);
  float*          X     = (float*)(ws + 100663296);
  float*          Y     = (float*)(ws + 117440512);
  unsigned short* A2    = (unsigned short*)(ws + 134217728);

  const float* kb = kvrg + 0 * (size_t)S_LEN * HIDN;
  const float* vb = kvrg + 1 * (size_t)S_LEN * HIDN;
  const float* rb = kvrg + 2 * (size_t)S_LEN * HIDN;
  const float* gb = kvrg + 3 * (size_t)S_LEN * HIDN;

  mix_kernel<<<dim3(S_LEN * HIDN / 256), 256, 0, stream>>>(hidden, tmk, tmv, tmr, tmg, mixed);

  // k,v,r,g = mixed[z] @ W[z]^T ; silu on z==3 (gate)
  gemm_bt<<<dim3(8, 32, 4), 256, 0, stream>>>(mixed, w_key, w_value, w_recep, w_gate,
                                              kvrg, S_LEN, HIDN, HIDN, 0x8);

  rec_pass1<<<dim3(NCH, NH), 64, 0, stream>>>(kb, vb, time_decay, X);
  rec_pass2<<<dim3(NH), 64, 0, stream>>>(time_decay, X, Y);
  rec_pass3<<<dim3(NCH, NH), 64, 0, stream>>>(kb, vb, rb, gb, time_decay, time_faaaa,
                                              gnw, gnb, Y, A2);

  // out = (g * groupnorm(o)) @ w_output^T
  gemm_bt<<<dim3(8, 32, 1), 256, 0, stream>>>(A2, w_output, w_output, w_output, w_output,
                                              out, S_LEN, HIDN, HIDN, 0x0);
}